// Round 3
// baseline (219.426 us; speedup 1.0000x reference)
//
#include <hip/hip_runtime.h>
#include <math.h>

#define S_DIM 256
#define B_DIM 16
#define F_DIM 200
#define H_DIM 100
#define ROWS (S_DIM * B_DIM)  // 4096

// ---------------------------------------------------------------------------
// K1: Eq = exp(2*(x@Wq)), Ek = exp(2*(x@Wk + b)) per row r = s*B+b.
// 8 rows/block, 256 threads = 2 f-halves x 128 h-lanes. x rows via uniform
// s_loads; W via coalesced vector loads. (unchanged from round 2 — ~5 us)
// ---------------------------------------------------------------------------
__global__ __launch_bounds__(256) void k1_proj_exp(
    const float* __restrict__ input, const float* __restrict__ Wq,
    const float* __restrict__ Wk, const float* __restrict__ bias,
    float* __restrict__ Eq, float* __restrict__ Ek)
{
    __shared__ float pq[8][128], pk[8][128];
    const int tid = threadIdx.x;
    const int h = tid & 127;
    const int fg = tid >> 7;
    const int hh = (h < H_DIM) ? h : (H_DIM - 1);
    const int r0 = blockIdx.x * 8;
    float accq[8], acck[8];
#pragma unroll
    for (int r = 0; r < 8; ++r) { accq[r] = 0.f; acck[r] = 0.f; }
    const int fb = fg * 100;
    for (int f4 = 0; f4 < 25; ++f4) {
        const int f = fb + f4 * 4;
        const float wq0 = Wq[(f + 0) * H_DIM + hh];
        const float wq1 = Wq[(f + 1) * H_DIM + hh];
        const float wq2 = Wq[(f + 2) * H_DIM + hh];
        const float wq3 = Wq[(f + 3) * H_DIM + hh];
        const float wk0 = Wk[(f + 0) * H_DIM + hh];
        const float wk1 = Wk[(f + 1) * H_DIM + hh];
        const float wk2 = Wk[(f + 2) * H_DIM + hh];
        const float wk3 = Wk[(f + 3) * H_DIM + hh];
#pragma unroll
        for (int r = 0; r < 8; ++r) {
            const float4 xv = *(const float4*)&input[(r0 + r) * F_DIM + f];
            accq[r] = fmaf(xv.x, wq0, accq[r]);
            accq[r] = fmaf(xv.y, wq1, accq[r]);
            accq[r] = fmaf(xv.z, wq2, accq[r]);
            accq[r] = fmaf(xv.w, wq3, accq[r]);
            acck[r] = fmaf(xv.x, wk0, acck[r]);
            acck[r] = fmaf(xv.y, wk1, acck[r]);
            acck[r] = fmaf(xv.z, wk2, acck[r]);
            acck[r] = fmaf(xv.w, wk3, acck[r]);
        }
    }
    if (fg) {
#pragma unroll
        for (int r = 0; r < 8; ++r) { pq[r][h] = accq[r]; pk[r][h] = acck[r]; }
    }
    __syncthreads();
    if (!fg && h < H_DIM) {
        const float bv = bias[h];
#pragma unroll
        for (int r = 0; r < 8; ++r) {
            const float q = accq[r] + pq[r][h];
            const float k = acck[r] + pk[r][h] + bv;
            Eq[(r0 + r) * H_DIM + h] = __expf(2.f * q);
            Ek[(r0 + r) * H_DIM + h] = __expf(2.f * k);
        }
    }
}

// ---------------------------------------------------------------------------
// K2: p[t,b,s] = exp( sumv - 2*sum_h v_h / (Eq*Ek + 1) ), t<len, s<len.
// 2-way fused denominators: vmx/dx+vmy/dy = (vmx*dy+vmy*dx)/(dx*dy)
//   -> 6 VALU + 1 rcp per 2 h-elements (rcp count halved vs round 2).
// Also emits per-s-tile partial row sums psum4[sy][t][b] via 64-lane
// butterfly (deterministic, no atomics, no init needed).
// ---------------------------------------------------------------------------
__global__ __launch_bounds__(256) void k2_scores(
    const float* __restrict__ Eq, const float* __restrict__ Ek,
    const float* __restrict__ vvec, const int* __restrict__ seqlen,
    float* __restrict__ p, float* __restrict__ psum4)
{
    __shared__ float4 klds[64 * 27];
    const int tid = threadIdx.x;
    const int b = blockIdx.z;
    const int len = seqlen[b];
    const int s0 = blockIdx.y * 64;
    const int t0 = blockIdx.x * 8;
    if (s0 >= len || t0 >= len) return;  // block-uniform
    const float4* Ek4 = (const float4*)Ek;
    for (int idx = tid; idx < 64 * 25; idx += 256) {
        int r = idx / 25, c = idx - r * 25;
        klds[r * 27 + c] = Ek4[((s0 + r) * B_DIM + b) * 25 + c];
    }
    __syncthreads();
    const int s = tid & 63;
    const int th = __builtin_amdgcn_readfirstlane(tid >> 6);
    const int tbase = t0 + th * 2;
    const int ni = len - tbase;
    if (ni <= 0) return;  // after the only barrier — safe

    float sv = 0.f;
    for (int h4 = 0; h4 < 25; ++h4) {
        const float4 vv = *(const float4*)&vvec[h4 * 4];
        sv += (vv.x + vv.y) + (vv.z + vv.w);
    }
    float acc0 = sv, acc1 = sv;
    const float* eq0 = Eq + ((tbase + 0) * B_DIM + b) * H_DIM;
    const float* eq1 = Eq + ((tbase + 1) * B_DIM + b) * H_DIM;  // row<=255 always
    for (int h4 = 0; h4 < 25; ++h4) {
        const float4 kk = klds[s * 27 + h4];
        const float4 vv = *(const float4*)&vvec[h4 * 4];
        const float4 q0 = *(const float4*)(eq0 + h4 * 4);
        const float4 q1 = *(const float4*)(eq1 + h4 * 4);
        const float vmx = -2.f * vv.x, vmy = -2.f * vv.y;
        const float vmz = -2.f * vv.z, vmw = -2.f * vv.w;
        {   // t row 0, pair (x,y) then (z,w)
            float dx = fmaf(q0.x, kk.x, 1.f), dy = fmaf(q0.y, kk.y, 1.f);
            float N = fmaf(vmx, dy, vmy * dx);
            acc0 = fmaf(N, __builtin_amdgcn_rcpf(dx * dy), acc0);
            float dz = fmaf(q0.z, kk.z, 1.f), dw = fmaf(q0.w, kk.w, 1.f);
            float M = fmaf(vmz, dw, vmw * dz);
            acc0 = fmaf(M, __builtin_amdgcn_rcpf(dz * dw), acc0);
        }
        {   // t row 1
            float dx = fmaf(q1.x, kk.x, 1.f), dy = fmaf(q1.y, kk.y, 1.f);
            float N = fmaf(vmx, dy, vmy * dx);
            acc1 = fmaf(N, __builtin_amdgcn_rcpf(dx * dy), acc1);
            float dz = fmaf(q1.z, kk.z, 1.f), dw = fmaf(q1.w, kk.w, 1.f);
            float M = fmaf(vmz, dw, vmw * dz);
            acc1 = fmaf(M, __builtin_amdgcn_rcpf(dz * dw), acc1);
        }
    }
    const int ss = s0 + s;
    float pe0 = 0.f, pe1 = 0.f;
    if (ss < len) {
        pe0 = __expf(acc0);
        p[((tbase + 0) * B_DIM + b) * S_DIM + ss] = pe0;
        if (ni > 1) {
            pe1 = __expf(acc1);
            p[((tbase + 1) * B_DIM + b) * S_DIM + ss] = pe1;
        }
    }
    for (int off = 32; off; off >>= 1) {
        pe0 += __shfl_xor(pe0, off);
        pe1 += __shfl_xor(pe1, off);
    }
    if (s == 0) {
        float* pp = psum4 + (blockIdx.y * S_DIM + tbase) * B_DIM + b;
        pp[0] = pe0;
        if (ni > 1) pp[B_DIM] = pe1;
    }
}

// ---------------------------------------------------------------------------
// K3: unnormalized attended[t,b,f] = sum_{s<len} p[t,s]*x[s,f].
// lane = f (coalesced x loads); the 16 p-rows per block are wave-uniform ->
// s_load_dwordx4 on the scalar pipe. acc[16] in regs, no LDS, no barriers.
// Kills round-2's 64-lines-per-instr uncoalesced p reads.
// ---------------------------------------------------------------------------
__global__ __launch_bounds__(256) void k3_attend(
    const float* __restrict__ p, const float* __restrict__ input,
    const int* __restrict__ seqlen, float* __restrict__ att)
{
    const int tid = threadIdx.x;
    const int b = blockIdx.y;
    const int len = seqlen[b];
    const int t0 = blockIdx.x * 16;
    if (t0 >= len) return;  // block-uniform
    const int f = (tid < F_DIM) ? tid : (F_DIM - 1);
    float acc[16];
#pragma unroll
    for (int i = 0; i < 16; ++i) acc[i] = 0.f;
    const float* pb = p + b * S_DIM;  // + t*B*S + s
    int s = 0;
    for (; s + 4 <= len; s += 4) {
        const float x0 = input[((s + 0) * B_DIM + b) * F_DIM + f];
        const float x1 = input[((s + 1) * B_DIM + b) * F_DIM + f];
        const float x2 = input[((s + 2) * B_DIM + b) * F_DIM + f];
        const float x3 = input[((s + 3) * B_DIM + b) * F_DIM + f];
#pragma unroll
        for (int i = 0; i < 16; ++i) {
            // uniform address -> s_load_dwordx4 (scalar pipe)
            const float4 pv = *(const float4*)&pb[(t0 + i) * B_DIM * S_DIM + s];
            acc[i] = fmaf(pv.x, x0, acc[i]);
            acc[i] = fmaf(pv.y, x1, acc[i]);
            acc[i] = fmaf(pv.z, x2, acc[i]);
            acc[i] = fmaf(pv.w, x3, acc[i]);
        }
    }
    for (; s < len; ++s) {  // tail 0..3
        const float xv = input[(s * B_DIM + b) * F_DIM + f];
#pragma unroll
        for (int i = 0; i < 16; ++i)
            acc[i] = fmaf(pb[(t0 + i) * B_DIM * S_DIM + s], xv, acc[i]);
    }
    if (tid < F_DIM) {
#pragma unroll
        for (int i = 0; i < 16; ++i)
            att[((t0 + i) * B_DIM + b) * F_DIM + tid] = acc[i];
    }
}

// ---------------------------------------------------------------------------
// K4: normalize by psum (rcp per t) + max/mean pool over valid t.
// 1 block per b, 1024 threads: 4-way t-split + LDS combine.
// ---------------------------------------------------------------------------
__global__ __launch_bounds__(1024) void k4_pool(
    const float* __restrict__ att, const float* __restrict__ psum4,
    const int* __restrict__ seqlen, float* __restrict__ out)
{
    __shared__ float smx[4][256];
    __shared__ float ssm[4][256];
    const int b = blockIdx.x;
    const int tid = threadIdx.x;
    const int f = tid & 255;
    const int q = tid >> 8;
    const int len = seqlen[b];
    const int nsy = (len + 63) >> 6;  // # of valid s-tiles, 1..4
    float mx = -INFINITY, sm = 0.f;
    if (f < F_DIM) {
        for (int t = q; t < len; t += 4) {
            float ps = psum4[t * B_DIM + b];  // sy=0 always valid (len>=1)
            for (int sy = 1; sy < nsy; ++sy)
                ps += psum4[(sy * S_DIM + t) * B_DIM + b];
            const float a = att[(t * B_DIM + b) * F_DIM + f] *
                            __builtin_amdgcn_rcpf(ps);
            mx = fmaxf(mx, a);
            sm += a;
        }
    }
    smx[q][f] = mx;
    ssm[q][f] = sm;
    __syncthreads();
    if (q == 0 && f < F_DIM) {
#pragma unroll
        for (int k = 1; k < 4; ++k) {
            mx = fmaxf(mx, smx[k][f]);
            sm += ssm[k][f];
        }
        out[b * (2 * F_DIM) + f] = mx;
        out[b * (2 * F_DIM) + F_DIM + f] = sm / (float)len;
    }
}

extern "C" void kernel_launch(void* const* d_in, const int* in_sizes, int n_in,
                              void* d_out, int out_size, void* d_ws, size_t ws_size,
                              hipStream_t stream)
{
    const float* input  = (const float*)d_in[0];
    const int*   seqlen = (const int*)d_in[1];
    const float* Wq     = (const float*)d_in[2];
    const float* Wk     = (const float*)d_in[3];
    const float* bias   = (const float*)d_in[4];
    const float* vvec   = (const float*)d_in[5];
    float* out = (float*)d_out;

    float* ws = (float*)d_ws;
    float* Eq    = ws;                           // 409600 floats
    float* Ek    = ws + 409600;                  // 409600 floats
    float* p     = ws + 819200;                  // 1048576 floats [t][b][s]
    float* psum4 = ws + 819200 + 1048576;        // 16384 floats [sy][t][b]
    float* att   = ws;                           // 819200 floats — aliases Eq/Ek (dead after K2)

    k1_proj_exp<<<ROWS / 8, 256, 0, stream>>>(input, Wq, Wk, bias, Eq, Ek);
    k2_scores<<<dim3(S_DIM / 8, S_DIM / 64, B_DIM), 256, 0, stream>>>(Eq, Ek, vvec, seqlen, p, psum4);
    k3_attend<<<dim3(S_DIM / 16, B_DIM), 256, 0, stream>>>(p, input, seqlen, att);
    k4_pool<<<B_DIM, 1024, 0, stream>>>(att, psum4, seqlen, out);
}

// Round 4
// 168.198 us; speedup vs baseline: 1.3046x; 1.3046x over previous
//
#include <hip/hip_runtime.h>
#include <math.h>

#define S_DIM 256
#define B_DIM 16
#define F_DIM 200
#define H_DIM 100
#define ROWS (S_DIM * B_DIM)  // 4096

// ---------------------------------------------------------------------------
// K1: Eq = exp(2*(x@Wq)), Ek = exp(2*(x@Wk + b)) per row r = s*B+b.
// 8 rows/block, 256 threads = 2 f-halves x 128 h-lanes. x rows via uniform
// s_loads; W via coalesced vector loads. (unchanged — not in top-5)
// ---------------------------------------------------------------------------
__global__ __launch_bounds__(256) void k1_proj_exp(
    const float* __restrict__ input, const float* __restrict__ Wq,
    const float* __restrict__ Wk, const float* __restrict__ bias,
    float* __restrict__ Eq, float* __restrict__ Ek)
{
    __shared__ float pq[8][128], pk[8][128];
    const int tid = threadIdx.x;
    const int h = tid & 127;
    const int fg = tid >> 7;
    const int hh = (h < H_DIM) ? h : (H_DIM - 1);
    const int r0 = blockIdx.x * 8;
    float accq[8], acck[8];
#pragma unroll
    for (int r = 0; r < 8; ++r) { accq[r] = 0.f; acck[r] = 0.f; }
    const int fb = fg * 100;
    for (int f4 = 0; f4 < 25; ++f4) {
        const int f = fb + f4 * 4;
        const float wq0 = Wq[(f + 0) * H_DIM + hh];
        const float wq1 = Wq[(f + 1) * H_DIM + hh];
        const float wq2 = Wq[(f + 2) * H_DIM + hh];
        const float wq3 = Wq[(f + 3) * H_DIM + hh];
        const float wk0 = Wk[(f + 0) * H_DIM + hh];
        const float wk1 = Wk[(f + 1) * H_DIM + hh];
        const float wk2 = Wk[(f + 2) * H_DIM + hh];
        const float wk3 = Wk[(f + 3) * H_DIM + hh];
#pragma unroll
        for (int r = 0; r < 8; ++r) {
            const float4 xv = *(const float4*)&input[(r0 + r) * F_DIM + f];
            accq[r] = fmaf(xv.x, wq0, accq[r]);
            accq[r] = fmaf(xv.y, wq1, accq[r]);
            accq[r] = fmaf(xv.z, wq2, accq[r]);
            accq[r] = fmaf(xv.w, wq3, accq[r]);
            acck[r] = fmaf(xv.x, wk0, acck[r]);
            acck[r] = fmaf(xv.y, wk1, acck[r]);
            acck[r] = fmaf(xv.z, wk2, acck[r]);
            acck[r] = fmaf(xv.w, wk3, acck[r]);
        }
    }
    if (fg) {
#pragma unroll
        for (int r = 0; r < 8; ++r) { pq[r][h] = accq[r]; pk[r][h] = acck[r]; }
    }
    __syncthreads();
    if (!fg && h < H_DIM) {
        const float bv = bias[h];
#pragma unroll
        for (int r = 0; r < 8; ++r) {
            const float q = accq[r] + pq[r][h];
            const float k = acck[r] + pk[r][h] + bv;
            Eq[(r0 + r) * H_DIM + h] = __expf(2.f * q);
            Ek[(r0 + r) * H_DIM + h] = __expf(2.f * k);
        }
    }
}

// ---------------------------------------------------------------------------
// K2: p[t,b,s] = exp( sumv - 2*sum_h v_h / (Eq*Ek + 1) ), t<len, s<len.
// 2-way fused denominators -> 6 VALU + 1 rcp per 2 h-elements.
// Emits per-s-tile partial row sums psum4[sy][t][b] (deterministic, no
// atomics). (unchanged — not in top-5)
// ---------------------------------------------------------------------------
__global__ __launch_bounds__(256) void k2_scores(
    const float* __restrict__ Eq, const float* __restrict__ Ek,
    const float* __restrict__ vvec, const int* __restrict__ seqlen,
    float* __restrict__ p, float* __restrict__ psum4)
{
    __shared__ float4 klds[64 * 27];
    const int tid = threadIdx.x;
    const int b = blockIdx.z;
    const int len = seqlen[b];
    const int s0 = blockIdx.y * 64;
    const int t0 = blockIdx.x * 8;
    if (s0 >= len || t0 >= len) return;  // block-uniform
    const float4* Ek4 = (const float4*)Ek;
    for (int idx = tid; idx < 64 * 25; idx += 256) {
        int r = idx / 25, c = idx - r * 25;
        klds[r * 27 + c] = Ek4[((s0 + r) * B_DIM + b) * 25 + c];
    }
    __syncthreads();
    const int s = tid & 63;
    const int th = __builtin_amdgcn_readfirstlane(tid >> 6);
    const int tbase = t0 + th * 2;
    const int ni = len - tbase;
    if (ni <= 0) return;  // after the only barrier — safe

    float sv = 0.f;
    for (int h4 = 0; h4 < 25; ++h4) {
        const float4 vv = *(const float4*)&vvec[h4 * 4];
        sv += (vv.x + vv.y) + (vv.z + vv.w);
    }
    float acc0 = sv, acc1 = sv;
    const float* eq0 = Eq + ((tbase + 0) * B_DIM + b) * H_DIM;
    const float* eq1 = Eq + ((tbase + 1) * B_DIM + b) * H_DIM;  // row<=255 always
    for (int h4 = 0; h4 < 25; ++h4) {
        const float4 kk = klds[s * 27 + h4];
        const float4 vv = *(const float4*)&vvec[h4 * 4];
        const float4 q0 = *(const float4*)(eq0 + h4 * 4);
        const float4 q1 = *(const float4*)(eq1 + h4 * 4);
        const float vmx = -2.f * vv.x, vmy = -2.f * vv.y;
        const float vmz = -2.f * vv.z, vmw = -2.f * vv.w;
        {
            float dx = fmaf(q0.x, kk.x, 1.f), dy = fmaf(q0.y, kk.y, 1.f);
            float N = fmaf(vmx, dy, vmy * dx);
            acc0 = fmaf(N, __builtin_amdgcn_rcpf(dx * dy), acc0);
            float dz = fmaf(q0.z, kk.z, 1.f), dw = fmaf(q0.w, kk.w, 1.f);
            float M = fmaf(vmz, dw, vmw * dz);
            acc0 = fmaf(M, __builtin_amdgcn_rcpf(dz * dw), acc0);
        }
        {
            float dx = fmaf(q1.x, kk.x, 1.f), dy = fmaf(q1.y, kk.y, 1.f);
            float N = fmaf(vmx, dy, vmy * dx);
            acc1 = fmaf(N, __builtin_amdgcn_rcpf(dx * dy), acc1);
            float dz = fmaf(q1.z, kk.z, 1.f), dw = fmaf(q1.w, kk.w, 1.f);
            float M = fmaf(vmz, dw, vmw * dz);
            acc1 = fmaf(M, __builtin_amdgcn_rcpf(dz * dw), acc1);
        }
    }
    const int ss = s0 + s;
    float pe0 = 0.f, pe1 = 0.f;
    if (ss < len) {
        pe0 = __expf(acc0);
        p[((tbase + 0) * B_DIM + b) * S_DIM + ss] = pe0;
        if (ni > 1) {
            pe1 = __expf(acc1);
            p[((tbase + 1) * B_DIM + b) * S_DIM + ss] = pe1;
        }
    }
    for (int off = 32; off; off >>= 1) {
        pe0 += __shfl_xor(pe0, off);
        pe1 += __shfl_xor(pe1, off);
    }
    if (s == 0) {
        float* pp = psum4 + (blockIdx.y * S_DIM + tbase) * B_DIM + b;
        pp[0] = pe0;
        if (ni > 1) pp[B_DIM] = pe1;
    }
}

// ---------------------------------------------------------------------------
// K3: attended GEMM + normalize + PARTIAL POOL, all in one block.
// lane = f (coalesced x loads); 16 wave-uniform p-rows via s_load_dwordx4.
// Epilogue: each lane reduces its own 16 t-values (no cross-lane!) into
// pmax/psm[tile][b][f]. Blocks with t0>=len write (-INF, 0) sentinels so the
// combine kernel is branch-free. Kills round-3's 64us latency-bound k4.
// ---------------------------------------------------------------------------
__global__ __launch_bounds__(256) void k3_attend_pool(
    const float* __restrict__ p, const float* __restrict__ input,
    const float* __restrict__ psum4, const int* __restrict__ seqlen,
    float* __restrict__ pmax, float* __restrict__ psm)
{
    const int tid = threadIdx.x;
    const int b = blockIdx.y;
    const int len = seqlen[b];
    const int tile = blockIdx.x;
    const int t0 = tile * 16;
    float* pmx_out = pmax + (tile * B_DIM + b) * F_DIM;
    float* psm_out = psm + (tile * B_DIM + b) * F_DIM;
    if (t0 >= len) {  // block-uniform: sentinel tile
        if (tid < F_DIM) { pmx_out[tid] = -INFINITY; psm_out[tid] = 0.f; }
        return;
    }
    const int f = (tid < F_DIM) ? tid : (F_DIM - 1);

    // per-t normalizers: sum the <=4 s-tile partials (uniform s_loads)
    const int nsy = (len + 63) >> 6;
    float rps[16];
#pragma unroll
    for (int i = 0; i < 16; ++i) {
        float ps = psum4[(t0 + i) * B_DIM + b];  // sy=0 always valid (len>=1)
        for (int sy = 1; sy < nsy; ++sy)
            ps += psum4[(sy * S_DIM + t0 + i) * B_DIM + b];
        rps[i] = ps;  // poison for t0+i>=len — masked in the pool below
    }

    float acc[16];
#pragma unroll
    for (int i = 0; i < 16; ++i) acc[i] = 0.f;
    const float* pb = p + b * S_DIM;  // + t*B*S + s
    int s = 0;
    for (; s + 4 <= len; s += 4) {
        const float x0 = input[((s + 0) * B_DIM + b) * F_DIM + f];
        const float x1 = input[((s + 1) * B_DIM + b) * F_DIM + f];
        const float x2 = input[((s + 2) * B_DIM + b) * F_DIM + f];
        const float x3 = input[((s + 3) * B_DIM + b) * F_DIM + f];
#pragma unroll
        for (int i = 0; i < 16; ++i) {
            // uniform address -> s_load_dwordx4 (scalar pipe)
            const float4 pv = *(const float4*)&pb[(t0 + i) * B_DIM * S_DIM + s];
            acc[i] = fmaf(pv.x, x0, acc[i]);
            acc[i] = fmaf(pv.y, x1, acc[i]);
            acc[i] = fmaf(pv.z, x2, acc[i]);
            acc[i] = fmaf(pv.w, x3, acc[i]);
        }
    }
    for (; s < len; ++s) {  // tail 0..3
        const float xv = input[(s * B_DIM + b) * F_DIM + f];
#pragma unroll
        for (int i = 0; i < 16; ++i)
            acc[i] = fmaf(pb[(t0 + i) * B_DIM * S_DIM + s], xv, acc[i]);
    }

    // normalize + in-register pool over this tile's valid t rows
    const int nv = len - t0;  // >=1 here; valid rows are i < min(nv,16)
    float mx = -INFINITY, sm = 0.f;
#pragma unroll
    for (int i = 0; i < 16; ++i) {
        const float a = acc[i] * __builtin_amdgcn_rcpf(rps[i]);
        const bool ok = (i < nv);
        mx = ok ? fmaxf(mx, a) : mx;
        sm = ok ? (sm + a) : sm;
    }
    if (tid < F_DIM) { pmx_out[tid] = mx; psm_out[tid] = sm; }
}

// ---------------------------------------------------------------------------
// K4: combine 16 tile-partials per (b,f). Fully unrolled -> 32 independent
// coalesced loads, one waitcnt batch. 3200 threads, ~2 us.
// ---------------------------------------------------------------------------
__global__ __launch_bounds__(256) void k4_combine(
    const float* __restrict__ pmax, const float* __restrict__ psm,
    const int* __restrict__ seqlen, float* __restrict__ out)
{
    const int idx = blockIdx.x * 256 + threadIdx.x;
    if (idx >= B_DIM * F_DIM) return;
    const int b = idx / F_DIM;
    const int f = idx - b * F_DIM;
    float mx = -INFINITY, sm = 0.f;
#pragma unroll
    for (int tile = 0; tile < 16; ++tile) {
        mx = fmaxf(mx, pmax[(tile * B_DIM + b) * F_DIM + f]);
        sm += psm[(tile * B_DIM + b) * F_DIM + f];
    }
    out[b * (2 * F_DIM) + f] = mx;
    out[b * (2 * F_DIM) + F_DIM + f] = sm / (float)seqlen[b];
}

extern "C" void kernel_launch(void* const* d_in, const int* in_sizes, int n_in,
                              void* d_out, int out_size, void* d_ws, size_t ws_size,
                              hipStream_t stream)
{
    const float* input  = (const float*)d_in[0];
    const int*   seqlen = (const int*)d_in[1];
    const float* Wq     = (const float*)d_in[2];
    const float* Wk     = (const float*)d_in[3];
    const float* bias   = (const float*)d_in[4];
    const float* vvec   = (const float*)d_in[5];
    float* out = (float*)d_out;

    float* ws = (float*)d_ws;
    float* Eq    = ws;                     // 409600 floats
    float* Ek    = ws + 409600;            // 409600 floats
    float* p     = ws + 819200;            // 1048576 floats [t][b][s]
    float* psum4 = ws + 1867776;           // 16384 floats [sy][t][b]
    float* pmax  = ws + 1884160;           // 51200 floats [tile][b][f]
    float* psm   = ws + 1935360;           // 51200 floats [tile][b][f]

    k1_proj_exp<<<ROWS / 8, 256, 0, stream>>>(input, Wq, Wk, bias, Eq, Ek);
    k2_scores<<<dim3(S_DIM / 8, S_DIM / 64, B_DIM), 256, 0, stream>>>(Eq, Ek, vvec, seqlen, p, psum4);
    k3_attend_pool<<<dim3(S_DIM / 16, B_DIM), 256, 0, stream>>>(p, input, psum4, seqlen, pmax, psm);
    k4_combine<<<(B_DIM * F_DIM + 255) / 256, 256, 0, stream>>>(pmax, psm, seqlen, out);
}

// Round 5
// 111.302 us; speedup vs baseline: 1.9714x; 1.5112x over previous
//
#include <hip/hip_runtime.h>
#include <math.h>

#define S_DIM 256
#define B_DIM 16
#define F_DIM 200
#define H_DIM 100
#define ROWS (S_DIM * B_DIM)  // 4096

// ---------------------------------------------------------------------------
// K1: Eq = exp(2*(x@Wq)), Ek = exp(2*(x@Wk + b)) per row r = s*B+b.
// 8 rows/block, 256 threads = 2 f-halves x 128 h-lanes. x rows via uniform
// s_loads; W via coalesced vector loads. (unchanged — not in top-5)
// ---------------------------------------------------------------------------
__global__ __launch_bounds__(256) void k1_proj_exp(
    const float* __restrict__ input, const float* __restrict__ Wq,
    const float* __restrict__ Wk, const float* __restrict__ bias,
    float* __restrict__ Eq, float* __restrict__ Ek)
{
    __shared__ float pq[8][128], pk[8][128];
    const int tid = threadIdx.x;
    const int h = tid & 127;
    const int fg = tid >> 7;
    const int hh = (h < H_DIM) ? h : (H_DIM - 1);
    const int r0 = blockIdx.x * 8;
    float accq[8], acck[8];
#pragma unroll
    for (int r = 0; r < 8; ++r) { accq[r] = 0.f; acck[r] = 0.f; }
    const int fb = fg * 100;
    for (int f4 = 0; f4 < 25; ++f4) {
        const int f = fb + f4 * 4;
        const float wq0 = Wq[(f + 0) * H_DIM + hh];
        const float wq1 = Wq[(f + 1) * H_DIM + hh];
        const float wq2 = Wq[(f + 2) * H_DIM + hh];
        const float wq3 = Wq[(f + 3) * H_DIM + hh];
        const float wk0 = Wk[(f + 0) * H_DIM + hh];
        const float wk1 = Wk[(f + 1) * H_DIM + hh];
        const float wk2 = Wk[(f + 2) * H_DIM + hh];
        const float wk3 = Wk[(f + 3) * H_DIM + hh];
#pragma unroll
        for (int r = 0; r < 8; ++r) {
            const float4 xv = *(const float4*)&input[(r0 + r) * F_DIM + f];
            accq[r] = fmaf(xv.x, wq0, accq[r]);
            accq[r] = fmaf(xv.y, wq1, accq[r]);
            accq[r] = fmaf(xv.z, wq2, accq[r]);
            accq[r] = fmaf(xv.w, wq3, accq[r]);
            acck[r] = fmaf(xv.x, wk0, acck[r]);
            acck[r] = fmaf(xv.y, wk1, acck[r]);
            acck[r] = fmaf(xv.z, wk2, acck[r]);
            acck[r] = fmaf(xv.w, wk3, acck[r]);
        }
    }
    if (fg) {
#pragma unroll
        for (int r = 0; r < 8; ++r) { pq[r][h] = accq[r]; pk[r][h] = acck[r]; }
    }
    __syncthreads();
    if (!fg && h < H_DIM) {
        const float bv = bias[h];
#pragma unroll
        for (int r = 0; r < 8; ++r) {
            const float q = accq[r] + pq[r][h];
            const float k = acck[r] + pk[r][h] + bv;
            Eq[(r0 + r) * H_DIM + h] = __expf(2.f * q);
            Ek[(r0 + r) * H_DIM + h] = __expf(2.f * k);
        }
    }
}

// ---------------------------------------------------------------------------
// K2: scores. Same inner loop as round 4 (2-way fused denominators: 6 VALU +
// 1 rcp per 2 h). NEW: epilogue transposes the 64s x 8t tile through LDS
// (pt[64][9], conflict-free) and stores p in [b][s][t] layout so K3's s-loop
// reads are lane-coalesced. psum4 machinery removed (K3 sums inline).
// All 8 t rows are computed unconditionally (t>=len columns hold finite
// garbage; K3 masks) — keeps all waves at the barriers.
// ---------------------------------------------------------------------------
__global__ __launch_bounds__(256) void k2_scores(
    const float* __restrict__ Eq, const float* __restrict__ Ek,
    const float* __restrict__ vvec, const int* __restrict__ seqlen,
    float* __restrict__ p)
{
    __shared__ float4 klds[64 * 27];
    __shared__ float pt[64][9];
    const int tid = threadIdx.x;
    const int b = blockIdx.z;
    const int len = seqlen[b];
    const int s0 = blockIdx.y * 64;
    const int t0 = blockIdx.x * 8;
    if (s0 >= len || t0 >= len) return;  // block-uniform, before any barrier
    const float4* Ek4 = (const float4*)Ek;
    for (int idx = tid; idx < 64 * 25; idx += 256) {
        int r = idx / 25, c = idx - r * 25;
        klds[r * 27 + c] = Ek4[((s0 + r) * B_DIM + b) * 25 + c];
    }
    __syncthreads();
    const int s = tid & 63;
    const int th = tid >> 6;
    const int tbase = t0 + th * 2;  // <= 255 always

    float sv = 0.f;
    for (int h4 = 0; h4 < 25; ++h4) {
        const float4 vv = *(const float4*)&vvec[h4 * 4];
        sv += (vv.x + vv.y) + (vv.z + vv.w);
    }
    float acc0 = sv, acc1 = sv;
    const float* eq0 = Eq + ((tbase + 0) * B_DIM + b) * H_DIM;
    const float* eq1 = Eq + ((tbase + 1) * B_DIM + b) * H_DIM;
    for (int h4 = 0; h4 < 25; ++h4) {
        const float4 kk = klds[s * 27 + h4];
        const float4 vv = *(const float4*)&vvec[h4 * 4];
        const float4 q0 = *(const float4*)(eq0 + h4 * 4);
        const float4 q1 = *(const float4*)(eq1 + h4 * 4);
        const float vmx = -2.f * vv.x, vmy = -2.f * vv.y;
        const float vmz = -2.f * vv.z, vmw = -2.f * vv.w;
        {
            float dx = fmaf(q0.x, kk.x, 1.f), dy = fmaf(q0.y, kk.y, 1.f);
            float N = fmaf(vmx, dy, vmy * dx);
            acc0 = fmaf(N, __builtin_amdgcn_rcpf(dx * dy), acc0);
            float dz = fmaf(q0.z, kk.z, 1.f), dw = fmaf(q0.w, kk.w, 1.f);
            float M = fmaf(vmz, dw, vmw * dz);
            acc0 = fmaf(M, __builtin_amdgcn_rcpf(dz * dw), acc0);
        }
        {
            float dx = fmaf(q1.x, kk.x, 1.f), dy = fmaf(q1.y, kk.y, 1.f);
            float N = fmaf(vmx, dy, vmy * dx);
            acc1 = fmaf(N, __builtin_amdgcn_rcpf(dx * dy), acc1);
            float dz = fmaf(q1.z, kk.z, 1.f), dw = fmaf(q1.w, kk.w, 1.f);
            float M = fmaf(vmz, dw, vmw * dz);
            acc1 = fmaf(M, __builtin_amdgcn_rcpf(dz * dw), acc1);
        }
    }
    // stage tile in LDS (pad 9 -> conflict-free), then coalesced-ish
    // transposed store: p[b][s0+sr][t0+tr]
    pt[s][th * 2 + 0] = __expf(acc0);
    pt[s][th * 2 + 1] = __expf(acc1);
    __syncthreads();
    float* pb = p + (b * S_DIM + s0) * S_DIM + t0;
#pragma unroll
    for (int v = tid; v < 512; v += 256) {
        const int sr = v >> 3, tr = v & 7;
        if (s0 + sr < len) pb[sr * S_DIM + tr] = pt[sr][tr];
    }
}

// ---------------------------------------------------------------------------
// K3: attended + normalize + full pool, ONE block per (f-tile of 8, b).
// lane = t (256 lanes = all t). p[b][s][t] reads are per-lane COALESCED
// dwords (fixes round-4's scattered-s_load latency trap); x[s][f0..7] staged
// once in 8 KB LDS, read via same-address broadcast ds_read_b128 (free).
// psum accumulated inline (1 add/s). Pool: butterfly over 64 lanes + 4-wave
// LDS combine -> writes out directly. k4 eliminated. Grid 400 blocks.
// ---------------------------------------------------------------------------
__global__ __launch_bounds__(256) void k3_attend_pool(
    const float* __restrict__ p, const float* __restrict__ input,
    const int* __restrict__ seqlen, float* __restrict__ out)
{
    __shared__ float4 xlds4[512];  // [s][2] : x[s][b][f0..f0+7]
    __shared__ float lm[4][8], ls[4][8];
    const int tid = threadIdx.x;
    const int b = blockIdx.y;
    const int len = seqlen[b];
    const int base = b * 50 + blockIdx.x * 2;  // float4 index of x[s=0][b][f0]
    const float4* in4 = (const float4*)input;
    for (int i = tid; i < 512; i += 256) {
        const int s = i >> 1, half = i & 1;
        xlds4[i] = in4[s * (B_DIM * 50) + base + half];
    }
    __syncthreads();

    float acc[8];
#pragma unroll
    for (int j = 0; j < 8; ++j) acc[j] = 0.f;
    float psum = 0.f;
    const float* pb = p + b * (S_DIM * S_DIM) + tid;  // + s*256
    int s = 0;
    for (; s + 4 <= len; s += 4) {
#pragma unroll
        for (int q = 0; q < 4; ++q) {
            const float pv = pb[(s + q) * S_DIM];      // coalesced dword
            const float4 xa = xlds4[(s + q) * 2];      // broadcast b128
            const float4 xb = xlds4[(s + q) * 2 + 1];  // broadcast b128
            psum += pv;
            acc[0] = fmaf(pv, xa.x, acc[0]);
            acc[1] = fmaf(pv, xa.y, acc[1]);
            acc[2] = fmaf(pv, xa.z, acc[2]);
            acc[3] = fmaf(pv, xa.w, acc[3]);
            acc[4] = fmaf(pv, xb.x, acc[4]);
            acc[5] = fmaf(pv, xb.y, acc[5]);
            acc[6] = fmaf(pv, xb.z, acc[6]);
            acc[7] = fmaf(pv, xb.w, acc[7]);
        }
    }
    for (; s < len; ++s) {  // tail 0..3
        const float pv = pb[s * S_DIM];
        const float4 xa = xlds4[s * 2];
        const float4 xb = xlds4[s * 2 + 1];
        psum += pv;
        acc[0] = fmaf(pv, xa.x, acc[0]);
        acc[1] = fmaf(pv, xa.y, acc[1]);
        acc[2] = fmaf(pv, xa.z, acc[2]);
        acc[3] = fmaf(pv, xa.w, acc[3]);
        acc[4] = fmaf(pv, xb.x, acc[4]);
        acc[5] = fmaf(pv, xb.y, acc[5]);
        acc[6] = fmaf(pv, xb.z, acc[6]);
        acc[7] = fmaf(pv, xb.w, acc[7]);
    }

    // normalize + pool over t (lane dimension)
    const float rp = __builtin_amdgcn_rcpf(psum);
    const bool ok = (tid < len);
    const int w = tid >> 6, lane = tid & 63;
#pragma unroll
    for (int j = 0; j < 8; ++j) {
        const float a = acc[j] * rp;
        float m = ok ? a : -INFINITY;
        float s2 = ok ? a : 0.f;
        for (int off = 32; off; off >>= 1) {
            m = fmaxf(m, __shfl_xor(m, off));
            s2 += __shfl_xor(s2, off);
        }
        if (lane == 0) { lm[w][j] = m; ls[w][j] = s2; }
    }
    __syncthreads();
    if (tid < 8) {
        float m = lm[0][tid], s2 = ls[0][tid];
#pragma unroll
        for (int g = 1; g < 4; ++g) { m = fmaxf(m, lm[g][tid]); s2 += ls[g][tid]; }
        const int f0 = blockIdx.x * 8;
        out[b * (2 * F_DIM) + f0 + tid] = m;
        out[b * (2 * F_DIM) + F_DIM + f0 + tid] = s2 / (float)len;
    }
}

extern "C" void kernel_launch(void* const* d_in, const int* in_sizes, int n_in,
                              void* d_out, int out_size, void* d_ws, size_t ws_size,
                              hipStream_t stream)
{
    const float* input  = (const float*)d_in[0];
    const int*   seqlen = (const int*)d_in[1];
    const float* Wq     = (const float*)d_in[2];
    const float* Wk     = (const float*)d_in[3];
    const float* bias   = (const float*)d_in[4];
    const float* vvec   = (const float*)d_in[5];
    float* out = (float*)d_out;

    float* ws = (float*)d_ws;
    float* Eq = ws;                 // 409600 floats
    float* Ek = ws + 409600;        // 409600 floats
    float* p  = ws + 819200;        // 1048576 floats, layout [b][s][t]

    k1_proj_exp<<<ROWS / 8, 256, 0, stream>>>(input, Wq, Wk, bias, Eq, Ek);
    k2_scores<<<dim3(S_DIM / 8, S_DIM / 64, B_DIM), 256, 0, stream>>>(Eq, Ek, vvec, seqlen, p);
    k3_attend_pool<<<dim3(F_DIM / 8, B_DIM), 256, 0, stream>>>(p, input, seqlen, out);
}